// Round 5
// baseline (2086.569 us; speedup 1.0000x reference)
//
#include <hip/hip_runtime.h>
#include <cmath>

#define H1    64
#define T1    50
#define T2    100
#define BATCH 8192
#define NB2   256        // sample-blocks of 32
#define NTILE 512        // global 16-sample tiles

typedef __attribute__((ext_vector_type(8))) short s16x8;
typedef __attribute__((ext_vector_type(4))) float f32x4;

#define MFMA16(a,b,c) __builtin_amdgcn_mfma_f32_16x16x32_bf16(a,b,c,0,0,0)

#define S_SIG  (-1.4426950408889634f)   // -1/ln2 : sigmoid gates (i,f,o)
#define S_TANH ( 2.8853900817779268f)   // +2/ln2 : tanh gate (g)

// ---- workspace byte offsets ----
#define OFF_FC1T  ((size_t)0)                                   // fp32 T1*BATCH
#define OFF_XF    ((size_t)1638400)                             // ushort T1*4*NTILE*64*8
#define OFF_WA1   ((size_t)(1638400 + 104857600))               // ushort 32768
#define OFF_WA2HH (OFF_WA1 + 65536)                             // ushort 32768
#define OFF_WA2IH (OFF_WA2HH + 65536)                           // ushort 65536
#define OFF_PART  (OFF_WA2IH + 131072)                          // fp32 2*T2*BATCH
#define OFF_BS    (OFF_PART + 6553600)                          // fp32 2*256 prescaled bias

__device__ __forceinline__ float rcp_(float x) { return __builtin_amdgcn_rcpf(x); }
__device__ __forceinline__ float exp2_(float x) {
#if __has_builtin(__builtin_amdgcn_exp2f)
    return __builtin_amdgcn_exp2f(x);
#else
    return exp2f(x);
#endif
}
__device__ __forceinline__ float sigp_(float e)  { return rcp_(1.f + exp2_(e)); }
__device__ __forceinline__ float tanhp_(float e) { return 1.f - 2.f * rcp_(1.f + exp2_(e)); }
__device__ __forceinline__ float tanhc_(float c) { return tanhp_(S_TANH * c); }
__device__ __forceinline__ float tanh_(float x)  { return tanhc_(x); }

__device__ __forceinline__ unsigned short bf16_rne(float x) {
    unsigned int u = __float_as_uint(x);
    u += 0x7fffu + ((u >> 16) & 1u);
    return (unsigned short)(u >> 16);
}
__device__ __forceinline__ float bf16f(unsigned short h) {
    return __uint_as_float(((unsigned int)h) << 16);
}

// ---------------- k_pre: weight frags (prescaled) + prescaled bias + fc1 + zero(part) ----------------
__global__ __launch_bounds__(256) void k_pre(
    const float* __restrict__ whh1f, const float* __restrict__ whh1b,
    const float* __restrict__ whh2f, const float* __restrict__ whh2b,
    const float* __restrict__ wih2f, const float* __restrict__ wih2b,
    const float* __restrict__ b2f,   const float* __restrict__ b2b,
    const float* __restrict__ x, const float* __restrict__ fc1w,
    const float* __restrict__ fc1b,
    unsigned short* __restrict__ WA1, unsigned short* __restrict__ WA2HH,
    unsigned short* __restrict__ WA2IH, float* __restrict__ fc1T,
    float* __restrict__ part, float* __restrict__ BS)
{
    __shared__ float wls[1000];
    __shared__ float bls[50];
    int tid = threadIdx.x;
    int blk = blockIdx.x;
    if (blk < 64) {
        int i = blk * 256 + tid;                    // 16384 slots
        if (i < 8192) {
            int a   = i >> 12;                      // 0: layer1 whh, 1: layer2 whh
            int r   = i & 4095;
            int dir = r >> 11, rem = r & 2047;
            int mt  = rem >> 7, rem2 = rem & 127;
            int kk  = rem2 >> 6, l = rem2 & 63;
            const float* s_ = a ? (dir ? whh2b : whh2f) : (dir ? whh1b : whh1f);
            unsigned short* d_ = a ? WA2HH : WA1;
            int gate = mt * 16 + (l & 15);
            float sc = ((gate >> 6) == 2) ? S_TANH : S_SIG;
            int k0   = kk * 32 + (l >> 4) * 8;
            const float* p = s_ + gate * 64 + k0;
            unsigned short* q = d_ + (size_t)r * 8;
#pragma unroll
            for (int j = 0; j < 8; ++j) q[j] = bf16_rne(p[j] * sc);
        } else {
            int r   = i - 8192;                     // layer2 wih, 8192 slots
            int dir = r >> 12, rem = r & 4095;
            int mt  = rem >> 8, rem2 = rem & 255;
            int kk  = rem2 >> 6, l = rem2 & 63;
            const float* s_ = dir ? wih2b : wih2f;
            int gate = mt * 16 + (l & 15);
            float sc = ((gate >> 6) == 2) ? S_TANH : S_SIG;
            int k0   = kk * 32 + (l >> 4) * 8;
            const float* p = s_ + gate * 128 + k0;
            unsigned short* q = WA2IH + (size_t)r * 8;
#pragma unroll
            for (int j = 0; j < 8; ++j) q[j] = bf16_rne(p[j] * sc);
        }
    } else if (blk < 96) {
        // fc1
        for (int i = tid; i < 1000; i += 256) wls[i] = fc1w[i];
        if (tid < 50) bls[tid] = fc1b[tid];
        __syncthreads();
        int bidx = (blk - 64) * 256 + tid;
        float xv[20];
#pragma unroll
        for (int i = 0; i < 20; ++i) xv[i] = x[bidx * 20 + i];
        for (int t = 0; t < T1; ++t) {
            float s = bls[t];
#pragma unroll
            for (int i = 0; i < 20; ++i) s += xv[i] * wls[t * 20 + i];
            fc1T[t * BATCH + bidx] = s;
        }
    } else if (blk < 352) {
        // zero the fc2 partial accumulator (atomicAdd target)
        const int n = 2 * T2 * BATCH;
        for (int i = (blk - 96) * 256 + tid; i < n; i += 256 * 256) part[i] = 0.f;
    } else {
        // prescaled layer-2 bias table: BS[dir*256 + m] = bias[m] * sc(m>>6)
        for (int i = tid; i < 512; i += 256) {
            int d = i >> 8, m = i & 255;
            const float* bb = d ? b2b : b2f;
            float sc = ((m >> 6) == 2) ? S_TANH : S_SIG;
            BS[i] = bb[m] * sc;
        }
    }
}

// ---------------- layer-1 BiLSTM: 4 blocks/CU ----------------
__global__ __launch_bounds__(512, 8) void k_lstm1(
    const float* __restrict__ wih1f, const float* __restrict__ b1f,
    const float* __restrict__ wih1b, const float* __restrict__ b1b,
    const unsigned short* __restrict__ WA1,
    const float* __restrict__ fc1T,
    unsigned short* __restrict__ XF)
{
    __shared__ float x1s[T1][32];
    __shared__ unsigned short Htf[2][2][2][2][64][8];   // [buf][half][kk][wsh][l][j]
    int tid  = threadIdx.x;
    int lane = tid & 63;
    int w    = __builtin_amdgcn_readfirstlane(tid >> 6);
    int wh   = w & 3, wsh = w >> 2;
    int quad = lane >> 4, col = lane & 15;
    int dir  = blockIdx.y, bblk = blockIdx.x;

    for (int i = tid; i < T1 * 32; i += 512) {
        int t = i >> 5, s = i & 31;
        x1s[t][s] = fc1T[t * BATCH + bblk * 32 + s];
    }
    const float* wih = dir ? wih1b : wih1f;
    const float* bia = dir ? b1b : b1f;
    f32x4 wvv[4], bvv[4];
#pragma unroll
    for (int g = 0; g < 4; ++g) {
        float sc = (g == 2) ? S_TANH : S_SIG;
#pragma unroll
        for (int r = 0; r < 4; ++r) {
            int gate = g * 64 + wh * 16 + quad * 4 + r;
            wvv[g][r] = wih[gate] * sc;
            bvv[g][r] = bia[gate] * sc;
        }
    }
    s16x8 whhA[4][2];
#pragma unroll
    for (int g = 0; g < 4; ++g)
#pragma unroll
        for (int kk = 0; kk < 2; ++kk)
            whhA[g][kk] = *(const s16x8*)(WA1 +
                ((size_t)((dir * 16 + (g * 4 + wh)) * 2 + kk) * 64 + lane) * 8);

    float c[4];
#pragma unroll
    for (int r = 0; r < 4; ++r) c[r] = 0.f;

    int lq  = 2 * (wh & 1) + (quad >> 1);
    int lp  = lq * 16 + col;
    int jo  = (quad & 1) * 4;
    int kkw = wh >> 1;
    int kk1 = dir * 2 + (wh >> 1);
    int gtile = bblk * 2 + wsh;
    __syncthreads();
    int buf = 0;
    for (int step = 0; step < T1; ++step) {
        int t = dir ? (T1 - 1 - step) : step;
        float xt = x1s[t][wsh * 16 + col];
        f32x4 acc[4];
#pragma unroll
        for (int g = 0; g < 4; ++g)
#pragma unroll
            for (int r = 0; r < 4; ++r)
                acc[g][r] = bvv[g][r] + wvv[g][r] * xt;
        if (step) {
#pragma unroll
            for (int hf = 0; hf < 2; ++hf) {
                s16x8 hb0 = *(const s16x8*)&Htf[buf][hf][0][wsh][lane][0];
                s16x8 hb1 = *(const s16x8*)&Htf[buf][hf][1][wsh][lane][0];
#pragma unroll
                for (int g = 0; g < 4; ++g) {
                    acc[g] = MFMA16(whhA[g][0], hb0, acc[g]);
                    acc[g] = MFMA16(whhA[g][1], hb1, acc[g]);
                }
            }
        }
        int nbuf = buf ^ 1;
        unsigned short hh[4], hl[4];
#pragma unroll
        for (int r = 0; r < 4; ++r) {
            float cc = sigp_(acc[1][r]) * c[r] + sigp_(acc[0][r]) * tanhp_(acc[2][r]);
            c[r] = cc;
            float h = sigp_(acc[3][r]) * tanhc_(cc);
            hh[r] = bf16_rne(h);
            hl[r] = bf16_rne(h - bf16f(hh[r]));
        }
        uint2 vhi, vlo;
        vhi.x = (unsigned)hh[0] | ((unsigned)hh[1] << 16);
        vhi.y = (unsigned)hh[2] | ((unsigned)hh[3] << 16);
        vlo.x = (unsigned)hl[0] | ((unsigned)hl[1] << 16);
        vlo.y = (unsigned)hl[2] | ((unsigned)hl[3] << 16);
        *(uint2*)&Htf[nbuf][0][kkw][wsh][lp][jo] = vhi;
        *(uint2*)&Htf[nbuf][1][kkw][wsh][lp][jo] = vlo;
        *(uint2*)(XF + ((((size_t)t * 4 + kk1) * NTILE + gtile) * 64 + lp) * 8 + jo) = vhi;
        __syncthreads();
        buf = nbuf;
    }
}

// ---------------- layer-2 BiLSTM: Wih from L2, 16 KB LDS, 4 blocks/CU ----------------
__global__ __launch_bounds__(512, 8) void k_lstm2(
    const float* __restrict__ BS,
    const float* __restrict__ fc2w,
    const unsigned short* __restrict__ WA2HH,
    const unsigned short* __restrict__ WA2IH,
    const unsigned short* __restrict__ XF,
    float* __restrict__ part)
{
    __shared__ unsigned short Htf[2][2][2][2][64][8];   // [buf][half][kk][wsh][l][j] 16 KB
    int tid  = threadIdx.x;
    int lane = tid & 63;
    int w    = __builtin_amdgcn_readfirstlane(tid >> 6);
    int wh   = w & 3, wsh = w >> 2;
    int quad = lane >> 4, col = lane & 15;
    int dir  = blockIdx.y, bblk = blockIdx.x;
    int gtile = bblk * 2 + wsh;

    float f2v[4];
#pragma unroll
    for (int r = 0; r < 4; ++r)
        f2v[r] = fc2w[dir * 64 + wh * 16 + quad * 4 + r];

    s16x8 whhA[4][2];
#pragma unroll
    for (int g = 0; g < 4; ++g)
#pragma unroll
        for (int kk = 0; kk < 2; ++kk)
            whhA[g][kk] = *(const s16x8*)(WA2HH +
                ((size_t)((dir * 16 + (g * 4 + wh)) * 2 + kk) * 64 + lane) * 8);

    // per-wave Wih fragment base (L2-resident, shared by all blocks of this dir)
    const unsigned short* wbase = WA2IH + ((size_t)dir * 16 + wh) * 4 * 64 * 8 + (size_t)lane * 8;
    const float4* bsp = (const float4*)(BS + dir * 256 + wh * 16 + quad * 4);

    float c[4];
#pragma unroll
    for (int r = 0; r < 4; ++r) c[r] = 0.f;

    int lq  = 2 * (wh & 1) + (quad >> 1);
    int lp  = lq * 16 + col;
    int jo  = (quad & 1) * 4;
    int kkw = wh >> 1;

    // preload pair 0 X-frags
    s16x8 xbC[4], xbN[4];
    {
        int tp0 = dir ? (T1 - 1) : 0;
#pragma unroll
        for (int kk = 0; kk < 4; ++kk)
            xbC[kk] = *(const s16x8*)(XF +
                (((size_t)(tp0 * 4 + kk) * NTILE + gtile) * 64 + lane) * 8);
    }
    f32x4 xacc[4];
    __syncthreads();
    int buf = 0;

    for (int step = 0; step < T2; ++step) {
        int t2 = dir ? (T2 - 1 - step) : step;
        if ((step & 1) == 0) {
            // input projection: Wih A-frags streamed from global (L1/L2 hit)
#pragma unroll
            for (int g = 0; g < 4; ++g) {
                float4 bv4 = bsp[g * 16];
                f32x4 a; a[0] = bv4.x; a[1] = bv4.y; a[2] = bv4.z; a[3] = bv4.w;
                const unsigned short* wg = wbase + (size_t)g * 4 * 4 * 64 * 8;
#pragma unroll
                for (int kk = 0; kk < 4; ++kk) {
                    s16x8 wa = *(const s16x8*)(wg + (size_t)kk * 64 * 8);
                    a = MFMA16(wa, xbC[kk], a);
                }
                xacc[g] = a;
            }
            // prefetch next pair's X-frags
            int tp  = t2 >> 1;
            int tpn = dir ? (tp > 0 ? tp - 1 : 0) : (tp < T1 - 1 ? tp + 1 : T1 - 1);
#pragma unroll
            for (int kk = 0; kk < 4; ++kk)
                xbN[kk] = *(const s16x8*)(XF +
                    (((size_t)(tpn * 4 + kk) * NTILE + gtile) * 64 + lane) * 8);
        }
        f32x4 acc[4];
        if (step) {
            s16x8 hb00 = *(const s16x8*)&Htf[buf][0][0][wsh][lane][0];
            s16x8 hb01 = *(const s16x8*)&Htf[buf][0][1][wsh][lane][0];
            s16x8 hb10 = *(const s16x8*)&Htf[buf][1][0][wsh][lane][0];
            s16x8 hb11 = *(const s16x8*)&Htf[buf][1][1][wsh][lane][0];
#pragma unroll
            for (int g = 0; g < 4; ++g) {
                f32x4 a = MFMA16(whhA[g][0], hb00, xacc[g]);
                a = MFMA16(whhA[g][1], hb01, a);
                a = MFMA16(whhA[g][0], hb10, a);
                a = MFMA16(whhA[g][1], hb11, a);
                acc[g] = a;
            }
        } else {
#pragma unroll
            for (int g = 0; g < 4; ++g) acc[g] = xacc[g];
        }
        int nbuf = buf ^ 1;
        unsigned int uhi[4];
        unsigned short hl[4];
        float pacc = 0.f;
#pragma unroll
        for (int r = 0; r < 4; ++r) {
            float cc = sigp_(acc[1][r]) * c[r] + sigp_(acc[0][r]) * tanhp_(acc[2][r]);
            c[r] = cc;
            float h = sigp_(acc[3][r]) * tanhc_(cc);
            pacc += f2v[r] * h;
            unsigned int u = __float_as_uint(h);
            uhi[r] = u & 0xFFFF0000u;                       // truncation hi
            hl[r]  = bf16_rne(h - __uint_as_float(uhi[r])); // exact residual, rne
        }
        uint2 vhi, vlo;
        vhi.x = (uhi[0] >> 16) | uhi[1];
        vhi.y = (uhi[2] >> 16) | uhi[3];
        vlo.x = (unsigned)hl[0] | ((unsigned)hl[1] << 16);
        vlo.y = (unsigned)hl[2] | ((unsigned)hl[3] << 16);
        *(uint2*)&Htf[nbuf][0][kkw][wsh][lp][jo] = vhi;
        *(uint2*)&Htf[nbuf][1][kkw][wsh][lp][jo] = vlo;
        pacc += __shfl_xor(pacc, 16);
        pacc += __shfl_xor(pacc, 32);
        if (lane < 16)
            atomicAdd(&part[((size_t)(dir * T2 + t2)) * BATCH + bblk * 32 + wsh * 16 + lane], pacc);
        __syncthreads();
        buf = nbuf;
        if (step & 1) {
#pragma unroll
            for (int kk = 0; kk < 4; ++kk) xbC[kk] = xbN[kk];
        }
    }
}

// ---------------- combine + tanh ----------------
__global__ __launch_bounds__(256) void k_fc2(const float* __restrict__ part,
                                             const float* __restrict__ fc2b,
                                             float* __restrict__ out) {
    int u = blockIdx.x * 256 + threadIdx.x;
    if (u >= BATCH * T2) return;
    int b = u / T2, t = u - b * T2;
    float p = part[(size_t)t * BATCH + b] + part[((size_t)T2 + t) * BATCH + b] + fc2b[0];
    out[u] = tanh_(p);
}

extern "C" void kernel_launch(void* const* d_in, const int* in_sizes, int n_in,
                              void* d_out, int out_size, void* d_ws, size_t ws_size,
                              hipStream_t stream) {
    const float* x      = (const float*)d_in[0];
    const float* fc1w   = (const float*)d_in[1];
    const float* fc1b   = (const float*)d_in[2];
    const float* r1wihf = (const float*)d_in[3];
    const float* r1whhf = (const float*)d_in[4];
    const float* r1bf   = (const float*)d_in[5];
    const float* r1wihb = (const float*)d_in[6];
    const float* r1whhb = (const float*)d_in[7];
    const float* r1bb   = (const float*)d_in[8];
    const float* r2wihf = (const float*)d_in[9];
    const float* r2whhf = (const float*)d_in[10];
    const float* r2bf   = (const float*)d_in[11];
    const float* r2wihb = (const float*)d_in[12];
    const float* r2whhb = (const float*)d_in[13];
    const float* r2bb   = (const float*)d_in[14];
    const float* fc2w   = (const float*)d_in[15];
    const float* fc2b   = (const float*)d_in[16];
    char* ws   = (char*)d_ws;
    float* out = (float*)d_out;

    float*          fc1T  = (float*)(ws + OFF_FC1T);
    unsigned short* XF    = (unsigned short*)(ws + OFF_XF);
    unsigned short* WA1   = (unsigned short*)(ws + OFF_WA1);
    unsigned short* WA2HH = (unsigned short*)(ws + OFF_WA2HH);
    unsigned short* WA2IH = (unsigned short*)(ws + OFF_WA2IH);
    float*          partp = (float*)(ws + OFF_PART);
    float*          BS    = (float*)(ws + OFF_BS);

    k_pre<<<353, 256, 0, stream>>>(r1whhf, r1whhb, r2whhf, r2whhb, r2wihf, r2wihb,
                                   r2bf, r2bb, x, fc1w, fc1b,
                                   WA1, WA2HH, WA2IH, fc1T, partp, BS);
    dim3 g1(NB2, 2);
    k_lstm1<<<g1, 512, 0, stream>>>(r1wihf, r1bf, r1wihb, r1bb, WA1, fc1T, XF);
    k_lstm2<<<g1, 512, 0, stream>>>(BS, fc2w, WA2HH, WA2IH, XF, partp);
    k_fc2<<<(BATCH * T2 + 255) / 256, 256, 0, stream>>>(partp, fc2b, out);
}

// Round 6
// 630.976 us; speedup vs baseline: 3.3069x; 3.3069x over previous
//
#include <hip/hip_runtime.h>
#include <cmath>

#define H1    64
#define T1    50
#define T2    100
#define BATCH 8192
#define NB    512        // sample-blocks of 16
#define NTILE 512        // global 16-sample tiles

typedef __attribute__((ext_vector_type(8))) short s16x8;
typedef __attribute__((ext_vector_type(4))) float f32x4;

#define MFMA16(a,b,c) __builtin_amdgcn_mfma_f32_16x16x32_bf16(a,b,c,0,0,0)

#define S_SIG  (-1.4426950408889634f)   // -1/ln2 : sigmoid gates (i,f,o)
#define S_TANH ( 2.8853900817779268f)   // +2/ln2 : tanh gate (g)

// ---- workspace byte offsets ----
#define OFF_FC1T  ((size_t)0)                                   // fp32 T1*BATCH
#define OFF_XF    ((size_t)1638400)                             // ushort T1*4*NTILE*64*8
#define OFF_WA1   ((size_t)(1638400 + 104857600))               // ushort 32768
#define OFF_WA2HH (OFF_WA1 + 65536)                             // ushort 32768
#define OFF_WA2IH (OFF_WA2HH + 65536)                           // ushort 65536
#define OFF_PART  (OFF_WA2IH + 131072)                          // fp32 2*T2*BATCH
#define OFF_BS    (OFF_PART + 6553600)                          // fp32 2*256 prescaled bias

__device__ __forceinline__ float rcp_(float x) { return __builtin_amdgcn_rcpf(x); }
__device__ __forceinline__ float exp2_(float x) {
#if __has_builtin(__builtin_amdgcn_exp2f)
    return __builtin_amdgcn_exp2f(x);
#else
    return exp2f(x);
#endif
}
__device__ __forceinline__ float sigp_(float e)  { return rcp_(1.f + exp2_(e)); }
__device__ __forceinline__ float tanhp_(float e) { return 1.f - 2.f * rcp_(1.f + exp2_(e)); }
__device__ __forceinline__ float tanhc_(float c) { return tanhp_(S_TANH * c); }
__device__ __forceinline__ float tanh_(float x)  { return tanhc_(x); }

__device__ __forceinline__ unsigned short bf16_rne(float x) {
    unsigned int u = __float_as_uint(x);
    u += 0x7fffu + ((u >> 16) & 1u);
    return (unsigned short)(u >> 16);
}
__device__ __forceinline__ float bf16f(unsigned short h) {
    return __uint_as_float(((unsigned int)h) << 16);
}

// ---------------- k_pre: weight frags (prescaled) + prescaled bias + fc1 + zero(part) ----------------
__global__ __launch_bounds__(256) void k_pre(
    const float* __restrict__ whh1f, const float* __restrict__ whh1b,
    const float* __restrict__ whh2f, const float* __restrict__ whh2b,
    const float* __restrict__ wih2f, const float* __restrict__ wih2b,
    const float* __restrict__ b2f,   const float* __restrict__ b2b,
    const float* __restrict__ x, const float* __restrict__ fc1w,
    const float* __restrict__ fc1b,
    unsigned short* __restrict__ WA1, unsigned short* __restrict__ WA2HH,
    unsigned short* __restrict__ WA2IH, float* __restrict__ fc1T,
    float* __restrict__ part, float* __restrict__ BS)
{
    __shared__ float wls[1000];
    __shared__ float bls[50];
    int tid = threadIdx.x;
    int blk = blockIdx.x;
    if (blk < 64) {
        int i = blk * 256 + tid;                    // 16384 slots
        if (i < 8192) {
            int a   = i >> 12;                      // 0: layer1 whh, 1: layer2 whh
            int r   = i & 4095;
            int dir = r >> 11, rem = r & 2047;
            int mt  = rem >> 7, rem2 = rem & 127;
            int kk  = rem2 >> 6, l = rem2 & 63;
            const float* s_ = a ? (dir ? whh2b : whh2f) : (dir ? whh1b : whh1f);
            unsigned short* d_ = a ? WA2HH : WA1;
            int gate = mt * 16 + (l & 15);
            float sc = ((gate >> 6) == 2) ? S_TANH : S_SIG;
            int k0   = kk * 32 + (l >> 4) * 8;
            const float* p = s_ + gate * 64 + k0;
            unsigned short* q = d_ + (size_t)r * 8;
#pragma unroll
            for (int j = 0; j < 8; ++j) q[j] = bf16_rne(p[j] * sc);
        } else {
            int r   = i - 8192;                     // layer2 wih, 8192 slots
            int dir = r >> 12, rem = r & 4095;
            int mt  = rem >> 8, rem2 = rem & 255;
            int kk  = rem2 >> 6, l = rem2 & 63;
            const float* s_ = dir ? wih2b : wih2f;
            int gate = mt * 16 + (l & 15);
            float sc = ((gate >> 6) == 2) ? S_TANH : S_SIG;
            int k0   = kk * 32 + (l >> 4) * 8;
            const float* p = s_ + gate * 128 + k0;
            unsigned short* q = WA2IH + (size_t)r * 8;
#pragma unroll
            for (int j = 0; j < 8; ++j) q[j] = bf16_rne(p[j] * sc);
        }
    } else if (blk < 96) {
        // fc1
        for (int i = tid; i < 1000; i += 256) wls[i] = fc1w[i];
        if (tid < 50) bls[tid] = fc1b[tid];
        __syncthreads();
        int bidx = (blk - 64) * 256 + tid;
        float xv[20];
#pragma unroll
        for (int i = 0; i < 20; ++i) xv[i] = x[bidx * 20 + i];
        for (int t = 0; t < T1; ++t) {
            float s = bls[t];
#pragma unroll
            for (int i = 0; i < 20; ++i) s += xv[i] * wls[t * 20 + i];
            fc1T[t * BATCH + bidx] = s;
        }
    } else if (blk < 352) {
        // zero the fc2 partial accumulator (atomicAdd target)
        const int n = 2 * T2 * BATCH;
        for (int i = (blk - 96) * 256 + tid; i < n; i += 256 * 256) part[i] = 0.f;
    } else {
        // prescaled layer-2 bias table: BS[dir*256 + m] = bias[m] * sc(m>>6)
        for (int i = tid; i < 512; i += 256) {
            int d = i >> 8, m = i & 255;
            const float* bb = d ? b2b : b2f;
            float sc = ((m >> 6) == 2) ? S_TANH : S_SIG;
            BS[i] = bb[m] * sc;
        }
    }
}

// ---------------- layer-1 BiLSTM: 16 samples/block, 4 waves ----------------
__global__ __launch_bounds__(256, 4) void k_lstm1(
    const float* __restrict__ wih1f, const float* __restrict__ b1f,
    const float* __restrict__ wih1b, const float* __restrict__ b1b,
    const unsigned short* __restrict__ WA1,
    const float* __restrict__ fc1T,
    unsigned short* __restrict__ XF)
{
    __shared__ float x1s[T1][16];
    __shared__ unsigned short Htf[2][2][2][64][8];      // [buf][half][kk][l][j] 8 KB
    int tid  = threadIdx.x;
    int lane = tid & 63;
    int wh   = __builtin_amdgcn_readfirstlane(tid >> 6);    // 0..3
    int quad = lane >> 4, col = lane & 15;
    int dir  = blockIdx.y, bblk = blockIdx.x;

    for (int i = tid; i < T1 * 16; i += 256) {
        int t = i >> 4, s = i & 15;
        x1s[t][s] = fc1T[t * BATCH + bblk * 16 + s];
    }
    const float* wih = dir ? wih1b : wih1f;
    const float* bia = dir ? b1b : b1f;
    f32x4 wvv[4], bvv[4];
#pragma unroll
    for (int g = 0; g < 4; ++g) {
        float sc = (g == 2) ? S_TANH : S_SIG;
#pragma unroll
        for (int r = 0; r < 4; ++r) {
            int gate = g * 64 + wh * 16 + quad * 4 + r;
            wvv[g][r] = wih[gate] * sc;
            bvv[g][r] = bia[gate] * sc;
        }
    }
    s16x8 whhA[4][2];
#pragma unroll
    for (int g = 0; g < 4; ++g)
#pragma unroll
        for (int kk = 0; kk < 2; ++kk)
            whhA[g][kk] = *(const s16x8*)(WA1 +
                ((size_t)((dir * 16 + (g * 4 + wh)) * 2 + kk) * 64 + lane) * 8);

    float c[4];
#pragma unroll
    for (int r = 0; r < 4; ++r) c[r] = 0.f;

    int lq  = 2 * (wh & 1) + (quad >> 1);
    int lp  = lq * 16 + col;
    int jo  = (quad & 1) * 4;
    int kkw = wh >> 1;
    int kk1 = dir * 2 + (wh >> 1);
    int gtile = bblk;
    __syncthreads();
    int buf = 0;
    for (int step = 0; step < T1; ++step) {
        int t = dir ? (T1 - 1 - step) : step;
        float xt = x1s[t][col];
        f32x4 acc[4];
#pragma unroll
        for (int g = 0; g < 4; ++g)
#pragma unroll
            for (int r = 0; r < 4; ++r)
                acc[g][r] = bvv[g][r] + wvv[g][r] * xt;
        if (step) {
#pragma unroll
            for (int hf = 0; hf < 2; ++hf) {
                s16x8 hb0 = *(const s16x8*)&Htf[buf][hf][0][lane][0];
                s16x8 hb1 = *(const s16x8*)&Htf[buf][hf][1][lane][0];
#pragma unroll
                for (int g = 0; g < 4; ++g) {
                    acc[g] = MFMA16(whhA[g][0], hb0, acc[g]);
                    acc[g] = MFMA16(whhA[g][1], hb1, acc[g]);
                }
            }
        }
        int nbuf = buf ^ 1;
        unsigned short hh[4], hl[4];
#pragma unroll
        for (int r = 0; r < 4; ++r) {
            float cc = sigp_(acc[1][r]) * c[r] + sigp_(acc[0][r]) * tanhp_(acc[2][r]);
            c[r] = cc;
            float h = sigp_(acc[3][r]) * tanhc_(cc);
            hh[r] = bf16_rne(h);
            hl[r] = bf16_rne(h - bf16f(hh[r]));
        }
        uint2 vhi, vlo;
        vhi.x = (unsigned)hh[0] | ((unsigned)hh[1] << 16);
        vhi.y = (unsigned)hh[2] | ((unsigned)hh[3] << 16);
        vlo.x = (unsigned)hl[0] | ((unsigned)hl[1] << 16);
        vlo.y = (unsigned)hl[2] | ((unsigned)hl[3] << 16);
        *(uint2*)&Htf[nbuf][0][kkw][lp][jo] = vhi;
        *(uint2*)&Htf[nbuf][1][kkw][lp][jo] = vlo;
        *(uint2*)(XF + ((((size_t)t * 4 + kk1) * NTILE + gtile) * 64 + lp) * 8 + jo) = vhi;
        __syncthreads();
        buf = nbuf;
    }
}

// ---------------- layer-2 BiLSTM: Wih from L2, 16 samples/block, 4 waves ----------------
__global__ __launch_bounds__(256, 4) void k_lstm2(
    const float* __restrict__ BS,
    const float* __restrict__ fc2w,
    const unsigned short* __restrict__ WA2HH,
    const unsigned short* __restrict__ WA2IH,
    const unsigned short* __restrict__ XF,
    float* __restrict__ part)
{
    __shared__ unsigned short Htf[2][2][2][64][8];      // [buf][half][kk][l][j] 8 KB
    int tid  = threadIdx.x;
    int lane = tid & 63;
    int wh   = __builtin_amdgcn_readfirstlane(tid >> 6);    // 0..3
    int quad = lane >> 4, col = lane & 15;
    int dir  = blockIdx.y, bblk = blockIdx.x;
    int gtile = bblk;

    float f2v[4];
#pragma unroll
    for (int r = 0; r < 4; ++r)
        f2v[r] = fc2w[dir * 64 + wh * 16 + quad * 4 + r];

    s16x8 whhA[4][2];
#pragma unroll
    for (int g = 0; g < 4; ++g)
#pragma unroll
        for (int kk = 0; kk < 2; ++kk)
            whhA[g][kk] = *(const s16x8*)(WA2HH +
                ((size_t)((dir * 16 + (g * 4 + wh)) * 2 + kk) * 64 + lane) * 8);

    // per-wave Wih fragment base (L2-resident, shared by all blocks of this dir)
    const unsigned short* wbase = WA2IH + ((size_t)dir * 16 + wh) * 4 * 64 * 8 + (size_t)lane * 8;
    const float4* bsp = (const float4*)(BS + dir * 256 + wh * 16 + quad * 4);

    float c[4];
#pragma unroll
    for (int r = 0; r < 4; ++r) c[r] = 0.f;

    int lq  = 2 * (wh & 1) + (quad >> 1);
    int lp  = lq * 16 + col;
    int jo  = (quad & 1) * 4;
    int kkw = wh >> 1;

    // preload pair 0 X-frags
    s16x8 xbC[4], xbN[4];
    {
        int tp0 = dir ? (T1 - 1) : 0;
#pragma unroll
        for (int kk = 0; kk < 4; ++kk)
            xbC[kk] = *(const s16x8*)(XF +
                (((size_t)(tp0 * 4 + kk) * NTILE + gtile) * 64 + lane) * 8);
    }
    f32x4 xacc[4];
    __syncthreads();
    int buf = 0;

    for (int step = 0; step < T2; ++step) {
        int t2 = dir ? (T2 - 1 - step) : step;
        if ((step & 1) == 0) {
            // input projection: Wih A-frags streamed from global (L1/L2 hit)
#pragma unroll
            for (int g = 0; g < 4; ++g) {
                float4 bv4 = bsp[g * 16];
                f32x4 a; a[0] = bv4.x; a[1] = bv4.y; a[2] = bv4.z; a[3] = bv4.w;
                const unsigned short* wg = wbase + (size_t)g * 4 * 4 * 64 * 8;
#pragma unroll
                for (int kk = 0; kk < 4; ++kk) {
                    s16x8 wa = *(const s16x8*)(wg + (size_t)kk * 64 * 8);
                    a = MFMA16(wa, xbC[kk], a);
                }
                xacc[g] = a;
            }
            // prefetch next pair's X-frags
            int tp  = t2 >> 1;
            int tpn = dir ? (tp > 0 ? tp - 1 : 0) : (tp < T1 - 1 ? tp + 1 : T1 - 1);
#pragma unroll
            for (int kk = 0; kk < 4; ++kk)
                xbN[kk] = *(const s16x8*)(XF +
                    (((size_t)(tpn * 4 + kk) * NTILE + gtile) * 64 + lane) * 8);
        }
        f32x4 acc[4];
        if (step) {
            s16x8 hb00 = *(const s16x8*)&Htf[buf][0][0][lane][0];
            s16x8 hb01 = *(const s16x8*)&Htf[buf][0][1][lane][0];
            s16x8 hb10 = *(const s16x8*)&Htf[buf][1][0][lane][0];
            s16x8 hb11 = *(const s16x8*)&Htf[buf][1][1][lane][0];
#pragma unroll
            for (int g = 0; g < 4; ++g) {
                f32x4 a = MFMA16(whhA[g][0], hb00, xacc[g]);
                a = MFMA16(whhA[g][1], hb01, a);
                a = MFMA16(whhA[g][0], hb10, a);
                a = MFMA16(whhA[g][1], hb11, a);
                acc[g] = a;
            }
        } else {
#pragma unroll
            for (int g = 0; g < 4; ++g) acc[g] = xacc[g];
        }
        int nbuf = buf ^ 1;
        unsigned int uhi[4];
        unsigned short hl[4];
        float pacc = 0.f;
#pragma unroll
        for (int r = 0; r < 4; ++r) {
            float cc = sigp_(acc[1][r]) * c[r] + sigp_(acc[0][r]) * tanhp_(acc[2][r]);
            c[r] = cc;
            float h = sigp_(acc[3][r]) * tanhc_(cc);
            pacc += f2v[r] * h;
            unsigned int u = __float_as_uint(h);
            uhi[r] = u & 0xFFFF0000u;                       // truncation hi
            hl[r]  = bf16_rne(h - __uint_as_float(uhi[r])); // exact residual, rne
        }
        uint2 vhi, vlo;
        vhi.x = (uhi[0] >> 16) | uhi[1];
        vhi.y = (uhi[2] >> 16) | uhi[3];
        vlo.x = (unsigned)hl[0] | ((unsigned)hl[1] << 16);
        vlo.y = (unsigned)hl[2] | ((unsigned)hl[3] << 16);
        *(uint2*)&Htf[nbuf][0][kkw][lp][jo] = vhi;
        *(uint2*)&Htf[nbuf][1][kkw][lp][jo] = vlo;
        pacc += __shfl_xor(pacc, 16);
        pacc += __shfl_xor(pacc, 32);
        if (lane < 16)
            atomicAdd(&part[((size_t)(dir * T2 + t2)) * BATCH + bblk * 16 + lane], pacc);
        __syncthreads();
        buf = nbuf;
        if (step & 1) {
#pragma unroll
            for (int kk = 0; kk < 4; ++kk) xbC[kk] = xbN[kk];
        }
    }
}

// ---------------- combine + tanh ----------------
__global__ __launch_bounds__(256) void k_fc2(const float* __restrict__ part,
                                             const float* __restrict__ fc2b,
                                             float* __restrict__ out) {
    int u = blockIdx.x * 256 + threadIdx.x;
    if (u >= BATCH * T2) return;
    int b = u / T2, t = u - b * T2;
    float p = part[(size_t)t * BATCH + b] + part[((size_t)T2 + t) * BATCH + b] + fc2b[0];
    out[u] = tanh_(p);
}

extern "C" void kernel_launch(void* const* d_in, const int* in_sizes, int n_in,
                              void* d_out, int out_size, void* d_ws, size_t ws_size,
                              hipStream_t stream) {
    const float* x      = (const float*)d_in[0];
    const float* fc1w   = (const float*)d_in[1];
    const float* fc1b   = (const float*)d_in[2];
    const float* r1wihf = (const float*)d_in[3];
    const float* r1whhf = (const float*)d_in[4];
    const float* r1bf   = (const float*)d_in[5];
    const float* r1wihb = (const float*)d_in[6];
    const float* r1whhb = (const float*)d_in[7];
    const float* r1bb   = (const float*)d_in[8];
    const float* r2wihf = (const float*)d_in[9];
    const float* r2whhf = (const float*)d_in[10];
    const float* r2bf   = (const float*)d_in[11];
    const float* r2wihb = (const float*)d_in[12];
    const float* r2whhb = (const float*)d_in[13];
    const float* r2bb   = (const float*)d_in[14];
    const float* fc2w   = (const float*)d_in[15];
    const float* fc2b   = (const float*)d_in[16];
    char* ws   = (char*)d_ws;
    float* out = (float*)d_out;

    float*          fc1T  = (float*)(ws + OFF_FC1T);
    unsigned short* XF    = (unsigned short*)(ws + OFF_XF);
    unsigned short* WA1   = (unsigned short*)(ws + OFF_WA1);
    unsigned short* WA2HH = (unsigned short*)(ws + OFF_WA2HH);
    unsigned short* WA2IH = (unsigned short*)(ws + OFF_WA2IH);
    float*          partp = (float*)(ws + OFF_PART);
    float*          BS    = (float*)(ws + OFF_BS);

    k_pre<<<353, 256, 0, stream>>>(r1whhf, r1whhb, r2whhf, r2whhb, r2wihf, r2wihb,
                                   r2bf, r2bb, x, fc1w, fc1b,
                                   WA1, WA2HH, WA2IH, fc1T, partp, BS);
    dim3 g1(NB, 2);
    k_lstm1<<<g1, 256, 0, stream>>>(r1wihf, r1bf, r1wihb, r1bb, WA1, fc1T, XF);
    k_lstm2<<<g1, 256, 0, stream>>>(BS, fc2w, WA2HH, WA2IH, XF, partp);
    k_fc2<<<(BATCH * T2 + 255) / 256, 256, 0, stream>>>(partp, fc2b, out);
}

// Round 7
// 414.216 us; speedup vs baseline: 5.0374x; 1.5233x over previous
//
#include <hip/hip_runtime.h>
#include <cmath>

#define H1    64
#define T1    50
#define T2    100
#define BATCH 8192
#define NB1   512        // lstm1 sample-blocks of 16
#define NB2   256        // lstm2 sample-blocks of 32
#define NTILE 512        // global 16-sample tiles

typedef __attribute__((ext_vector_type(8))) short s16x8;
typedef __attribute__((ext_vector_type(4))) float f32x4;

#define MFMA16(a,b,c) __builtin_amdgcn_mfma_f32_16x16x32_bf16(a,b,c,0,0,0)

#define S_SIG  (-1.4426950408889634f)   // -1/ln2 : sigmoid gates (i,f,o)
#define S_TANH ( 2.8853900817779268f)   // +2/ln2 : tanh gate (g)

// ---- workspace byte offsets ----
#define OFF_FC1T  ((size_t)0)                                   // fp32 T1*BATCH
#define OFF_XF    ((size_t)1638400)                             // ushort T1*4*NTILE*64*8
#define OFF_WA1   ((size_t)(1638400 + 104857600))               // ushort 32768
#define OFF_WA2HH (OFF_WA1 + 65536)                             // ushort 32768
#define OFF_WA2IH (OFF_WA2HH + 65536)                           // ushort 65536
#define OFF_PART  (OFF_WA2IH + 131072)                          // fp32 2*T2*BATCH
#define OFF_BS    (OFF_PART + 6553600)                          // fp32 2*256 prescaled bias

__device__ __forceinline__ float rcp_(float x) { return __builtin_amdgcn_rcpf(x); }
__device__ __forceinline__ float exp2_(float x) {
#if __has_builtin(__builtin_amdgcn_exp2f)
    return __builtin_amdgcn_exp2f(x);
#else
    return exp2f(x);
#endif
}
__device__ __forceinline__ float sigp_(float e)  { return rcp_(1.f + exp2_(e)); }
__device__ __forceinline__ float tanhp_(float e) { return 1.f - 2.f * rcp_(1.f + exp2_(e)); }
__device__ __forceinline__ float tanhc_(float c) { return tanhp_(S_TANH * c); }
__device__ __forceinline__ float tanh_(float x)  { return tanhc_(x); }

__device__ __forceinline__ unsigned short bf16_rne(float x) {
    unsigned int u = __float_as_uint(x);
    u += 0x7fffu + ((u >> 16) & 1u);
    return (unsigned short)(u >> 16);
}
__device__ __forceinline__ float bf16f(unsigned short h) {
    return __uint_as_float(((unsigned int)h) << 16);
}

// ---------------- k_pre: weight frags (prescaled) + prescaled bias + fc1 + zero(part) ----------------
__global__ __launch_bounds__(256) void k_pre(
    const float* __restrict__ whh1f, const float* __restrict__ whh1b,
    const float* __restrict__ whh2f, const float* __restrict__ whh2b,
    const float* __restrict__ wih2f, const float* __restrict__ wih2b,
    const float* __restrict__ b2f,   const float* __restrict__ b2b,
    const float* __restrict__ x, const float* __restrict__ fc1w,
    const float* __restrict__ fc1b,
    unsigned short* __restrict__ WA1, unsigned short* __restrict__ WA2HH,
    unsigned short* __restrict__ WA2IH, float* __restrict__ fc1T,
    float* __restrict__ part, float* __restrict__ BS)
{
    __shared__ float wls[1000];
    __shared__ float bls[50];
    int tid = threadIdx.x;
    int blk = blockIdx.x;
    if (blk < 64) {
        int i = blk * 256 + tid;                    // 16384 slots
        if (i < 8192) {
            int a   = i >> 12;                      // 0: layer1 whh, 1: layer2 whh
            int r   = i & 4095;
            int dir = r >> 11, rem = r & 2047;
            int mt  = rem >> 7, rem2 = rem & 127;
            int kk  = rem2 >> 6, l = rem2 & 63;
            const float* s_ = a ? (dir ? whh2b : whh2f) : (dir ? whh1b : whh1f);
            unsigned short* d_ = a ? WA2HH : WA1;
            int gate = mt * 16 + (l & 15);
            float sc = ((gate >> 6) == 2) ? S_TANH : S_SIG;
            int k0   = kk * 32 + (l >> 4) * 8;
            const float* p = s_ + gate * 64 + k0;
            unsigned short* q = d_ + (size_t)r * 8;
#pragma unroll
            for (int j = 0; j < 8; ++j) q[j] = bf16_rne(p[j] * sc);
        } else {
            int r   = i - 8192;                     // layer2 wih, 8192 slots
            int dir = r >> 12, rem = r & 4095;
            int mt  = rem >> 8, rem2 = rem & 255;
            int kk  = rem2 >> 6, l = rem2 & 63;
            const float* s_ = dir ? wih2b : wih2f;
            int gate = mt * 16 + (l & 15);
            float sc = ((gate >> 6) == 2) ? S_TANH : S_SIG;
            int k0   = kk * 32 + (l >> 4) * 8;
            const float* p = s_ + gate * 128 + k0;
            unsigned short* q = WA2IH + (size_t)r * 8;
#pragma unroll
            for (int j = 0; j < 8; ++j) q[j] = bf16_rne(p[j] * sc);
        }
    } else if (blk < 96) {
        // fc1
        for (int i = tid; i < 1000; i += 256) wls[i] = fc1w[i];
        if (tid < 50) bls[tid] = fc1b[tid];
        __syncthreads();
        int bidx = (blk - 64) * 256 + tid;
        float xv[20];
#pragma unroll
        for (int i = 0; i < 20; ++i) xv[i] = x[bidx * 20 + i];
        for (int t = 0; t < T1; ++t) {
            float s = bls[t];
#pragma unroll
            for (int i = 0; i < 20; ++i) s += xv[i] * wls[t * 20 + i];
            fc1T[t * BATCH + bidx] = s;
        }
    } else if (blk < 352) {
        // zero the fc2 partial accumulator (atomicAdd target)
        const int n = 2 * T2 * BATCH;
        for (int i = (blk - 96) * 256 + tid; i < n; i += 256 * 256) part[i] = 0.f;
    } else {
        // prescaled layer-2 bias table: BS[dir*256 + m] = bias[m] * sc(m>>6)
        for (int i = tid; i < 512; i += 256) {
            int d = i >> 8, m = i & 255;
            const float* bb = d ? b2b : b2f;
            float sc = ((m >> 6) == 2) ? S_TANH : S_SIG;
            BS[i] = bb[m] * sc;
        }
    }
}

// ---------------- layer-1 BiLSTM: 16 samples/block, 4 waves; XF store post-barrier ----------------
__global__ __launch_bounds__(256, 4) void k_lstm1(
    const float* __restrict__ wih1f, const float* __restrict__ b1f,
    const float* __restrict__ wih1b, const float* __restrict__ b1b,
    const unsigned short* __restrict__ WA1,
    const float* __restrict__ fc1T,
    unsigned short* __restrict__ XF)
{
    __shared__ float x1s[T1][16];
    __shared__ unsigned short Htf[2][2][2][64][8];      // [buf][half][kk][l][j] 8 KB
    int tid  = threadIdx.x;
    int lane = tid & 63;
    int wh   = __builtin_amdgcn_readfirstlane(tid >> 6);    // 0..3
    int quad = lane >> 4, col = lane & 15;
    int dir  = blockIdx.y, bblk = blockIdx.x;

    for (int i = tid; i < T1 * 16; i += 256) {
        int t = i >> 4, s = i & 15;
        x1s[t][s] = fc1T[t * BATCH + bblk * 16 + s];
    }
    const float* wih = dir ? wih1b : wih1f;
    const float* bia = dir ? b1b : b1f;
    f32x4 wvv[4], bvv[4];
#pragma unroll
    for (int g = 0; g < 4; ++g) {
        float sc = (g == 2) ? S_TANH : S_SIG;
#pragma unroll
        for (int r = 0; r < 4; ++r) {
            int gate = g * 64 + wh * 16 + quad * 4 + r;
            wvv[g][r] = wih[gate] * sc;
            bvv[g][r] = bia[gate] * sc;
        }
    }
    s16x8 whhA[4][2];
#pragma unroll
    for (int g = 0; g < 4; ++g)
#pragma unroll
        for (int kk = 0; kk < 2; ++kk)
            whhA[g][kk] = *(const s16x8*)(WA1 +
                ((size_t)((dir * 16 + (g * 4 + wh)) * 2 + kk) * 64 + lane) * 8);

    float c[4];
#pragma unroll
    for (int r = 0; r < 4; ++r) c[r] = 0.f;

    int lq  = 2 * (wh & 1) + (quad >> 1);
    int lp  = lq * 16 + col;
    int jo  = (quad & 1) * 4;
    int kkw = wh >> 1;
    int kk1 = dir * 2 + (wh >> 1);
    int gtile = bblk;
    __syncthreads();
    int buf = 0;
    for (int step = 0; step < T1; ++step) {
        int t = dir ? (T1 - 1 - step) : step;
        float xt = x1s[t][col];
        f32x4 acc[4];
#pragma unroll
        for (int g = 0; g < 4; ++g)
#pragma unroll
            for (int r = 0; r < 4; ++r)
                acc[g][r] = bvv[g][r] + wvv[g][r] * xt;
        if (step) {
#pragma unroll
            for (int hf = 0; hf < 2; ++hf) {
                s16x8 hb0 = *(const s16x8*)&Htf[buf][hf][0][lane][0];
                s16x8 hb1 = *(const s16x8*)&Htf[buf][hf][1][lane][0];
#pragma unroll
                for (int g = 0; g < 4; ++g) {
                    acc[g] = MFMA16(whhA[g][0], hb0, acc[g]);
                    acc[g] = MFMA16(whhA[g][1], hb1, acc[g]);
                }
            }
        }
        int nbuf = buf ^ 1;
        unsigned short hh[4], hl[4];
#pragma unroll
        for (int r = 0; r < 4; ++r) {
            float cc = sigp_(acc[1][r]) * c[r] + sigp_(acc[0][r]) * tanhp_(acc[2][r]);
            c[r] = cc;
            float h = sigp_(acc[3][r]) * tanhc_(cc);
            hh[r] = bf16_rne(h);
            hl[r] = bf16_rne(h - bf16f(hh[r]));
        }
        uint2 vhi, vlo;
        vhi.x = (unsigned)hh[0] | ((unsigned)hh[1] << 16);
        vhi.y = (unsigned)hh[2] | ((unsigned)hh[3] << 16);
        vlo.x = (unsigned)hl[0] | ((unsigned)hl[1] << 16);
        vlo.y = (unsigned)hl[2] | ((unsigned)hl[3] << 16);
        *(uint2*)&Htf[nbuf][0][kkw][lp][jo] = vhi;
        *(uint2*)&Htf[nbuf][1][kkw][lp][jo] = vlo;
        __syncthreads();
        // post-barrier: full step of slack before next barrier's vmcnt drain
        *(uint2*)(XF + ((((size_t)t * 4 + kk1) * NTILE + gtile) * 64 + lp) * 8 + jo) = vhi;
        buf = nbuf;
    }
}

// ---------------- layer-2 BiLSTM: Wih in LDS, off-path input proj, post-barrier atomics ----------------
__global__ __launch_bounds__(512, 4) void k_lstm2(
    const float* __restrict__ BS,
    const float* __restrict__ fc2w,
    const unsigned short* __restrict__ WA2HH,
    const unsigned short* __restrict__ WA2IH,
    const unsigned short* __restrict__ XF,
    float* __restrict__ part)
{
    __shared__ unsigned short wAl[16][4][64][8];        // 64 KB: dir slice of WA2IH
    __shared__ unsigned short Htf[2][2][2][2][64][8];   // [buf][half][kk][wsh][l][j] 16 KB
    int tid  = threadIdx.x;
    int lane = tid & 63;
    int w    = __builtin_amdgcn_readfirstlane(tid >> 6);
    int wh   = w & 3, wsh = w >> 2;
    int quad = lane >> 4, col = lane & 15;
    int dir  = blockIdx.y, bblk = blockIdx.x;
    int gtile = bblk * 2 + wsh;

    {   // stage Wih A-fragments (our dir) into LDS
        const uint4* src = (const uint4*)(WA2IH + (size_t)dir * 32768);
        uint4* dst = (uint4*)&wAl[0][0][0][0];
        for (int i = tid; i < 4096; i += 512) dst[i] = src[i];
    }
    float f2v[4];
#pragma unroll
    for (int r = 0; r < 4; ++r)
        f2v[r] = fc2w[dir * 64 + wh * 16 + quad * 4 + r];

    s16x8 whhA[4][2];
#pragma unroll
    for (int g = 0; g < 4; ++g)
#pragma unroll
        for (int kk = 0; kk < 2; ++kk)
            whhA[g][kk] = *(const s16x8*)(WA2HH +
                ((size_t)((dir * 16 + (g * 4 + wh)) * 2 + kk) * 64 + lane) * 8);

    const float4* bsp = (const float4*)(BS + dir * 256 + wh * 16 + quad * 4);

    float c[4];
#pragma unroll
    for (int r = 0; r < 4; ++r) c[r] = 0.f;

    int lq  = 2 * (wh & 1) + (quad >> 1);
    int lp  = lq * 16 + col;
    int jo  = (quad & 1) * 4;
    int kkw = wh >> 1;

    // preload pair-0 X-frags, compute pair-0 xacc after staging barrier
    s16x8 xbN[4];
    {
        int tp0 = dir ? (T1 - 1) : 0;
#pragma unroll
        for (int kk = 0; kk < 4; ++kk)
            xbN[kk] = *(const s16x8*)(XF +
                (((size_t)(tp0 * 4 + kk) * NTILE + gtile) * 64 + lane) * 8);
    }
    __syncthreads();
    f32x4 xaccC[4], xaccN[4];
#pragma unroll
    for (int g = 0; g < 4; ++g) {
        float4 bv4 = bsp[g * 16];
        f32x4 a; a[0] = bv4.x; a[1] = bv4.y; a[2] = bv4.z; a[3] = bv4.w;
#pragma unroll
        for (int kk = 0; kk < 4; ++kk) {
            s16x8 wa = *(const s16x8*)&wAl[g * 4 + wh][kk][lane][0];
            a = MFMA16(wa, xbN[kk], a);
        }
        xaccC[g] = a;
    }
    {   // prefetch pair-1 X-frags
        int tp1 = dir ? (T1 - 2) : 1;
#pragma unroll
        for (int kk = 0; kk < 4; ++kk)
            xbN[kk] = *(const s16x8*)(XF +
                (((size_t)(tp1 * 4 + kk) * NTILE + gtile) * 64 + lane) * 8);
    }
    int buf = 0;

    for (int step = 0; step < T2; ++step) {
        int t2 = dir ? (T2 - 1 - step) : step;
        f32x4 acc[4];
        if (step) {
            s16x8 hb00 = *(const s16x8*)&Htf[buf][0][0][wsh][lane][0];
            s16x8 hb01 = *(const s16x8*)&Htf[buf][0][1][wsh][lane][0];
            s16x8 hb10 = *(const s16x8*)&Htf[buf][1][0][wsh][lane][0];
            s16x8 hb11 = *(const s16x8*)&Htf[buf][1][1][wsh][lane][0];
#pragma unroll
            for (int g = 0; g < 4; ++g) {
                f32x4 a = MFMA16(whhA[g][0], hb00, xaccC[g]);
                a = MFMA16(whhA[g][1], hb01, a);
                a = MFMA16(whhA[g][0], hb10, a);
                a = MFMA16(whhA[g][1], hb11, a);
                acc[g] = a;
            }
        } else {
#pragma unroll
            for (int g = 0; g < 4; ++g) acc[g] = xaccC[g];
        }
        // odd steps: compute NEXT pair's input projection off the critical path,
        // then reload xbN with the pair-after-next X-frags (2 steps of slack)
        if ((step & 1) && step < T2 - 1) {
            int pn = (step >> 1) + 1;               // next pair index
#pragma unroll
            for (int g = 0; g < 4; ++g) {
                float4 bv4 = bsp[g * 16];
                f32x4 a; a[0] = bv4.x; a[1] = bv4.y; a[2] = bv4.z; a[3] = bv4.w;
#pragma unroll
                for (int kk = 0; kk < 4; ++kk) {
                    s16x8 wa = *(const s16x8*)&wAl[g * 4 + wh][kk][lane][0];
                    a = MFMA16(wa, xbN[kk], a);
                }
                xaccN[g] = a;
            }
            int pn2 = (pn + 1 < T1) ? pn + 1 : T1 - 1;
            int tpn2 = dir ? (T1 - 1 - pn2) : pn2;
#pragma unroll
            for (int kk = 0; kk < 4; ++kk)
                xbN[kk] = *(const s16x8*)(XF +
                    (((size_t)(tpn2 * 4 + kk) * NTILE + gtile) * 64 + lane) * 8);
        }
        int nbuf = buf ^ 1;
        unsigned int uhi[4];
        unsigned short hl[4];
        float pacc = 0.f;
#pragma unroll
        for (int r = 0; r < 4; ++r) {
            float cc = sigp_(acc[1][r]) * c[r] + sigp_(acc[0][r]) * tanhp_(acc[2][r]);
            c[r] = cc;
            float h = sigp_(acc[3][r]) * tanhc_(cc);
            pacc += f2v[r] * h;
            unsigned int u = __float_as_uint(h);
            uhi[r] = u & 0xFFFF0000u;                       // truncation hi
            hl[r]  = bf16_rne(h - __uint_as_float(uhi[r])); // exact residual, rne
        }
        uint2 vhi, vlo;
        vhi.x = (uhi[0] >> 16) | uhi[1];
        vhi.y = (uhi[2] >> 16) | uhi[3];
        vlo.x = (unsigned)hl[0] | ((unsigned)hl[1] << 16);
        vlo.y = (unsigned)hl[2] | ((unsigned)hl[3] << 16);
        *(uint2*)&Htf[nbuf][0][kkw][wsh][lp][jo] = vhi;
        *(uint2*)&Htf[nbuf][1][kkw][wsh][lp][jo] = vlo;
        pacc += __shfl_xor(pacc, 16);
        pacc += __shfl_xor(pacc, 32);
        __syncthreads();
        // post-barrier: atomic has a full step to retire before the next drain
        if (lane < 16)
            atomicAdd(&part[((size_t)(dir * T2 + t2)) * BATCH + bblk * 32 + wsh * 16 + lane], pacc);
        if (step & 1) {
#pragma unroll
            for (int g = 0; g < 4; ++g) xaccC[g] = xaccN[g];
        }
        buf = nbuf;
    }
}

// ---------------- combine + tanh ----------------
__global__ __launch_bounds__(256) void k_fc2(const float* __restrict__ part,
                                             const float* __restrict__ fc2b,
                                             float* __restrict__ out) {
    int u = blockIdx.x * 256 + threadIdx.x;
    if (u >= BATCH * T2) return;
    int b = u / T2, t = u - b * T2;
    float p = part[(size_t)t * BATCH + b] + part[((size_t)T2 + t) * BATCH + b] + fc2b[0];
    out[u] = tanh_(p);
}

extern "C" void kernel_launch(void* const* d_in, const int* in_sizes, int n_in,
                              void* d_out, int out_size, void* d_ws, size_t ws_size,
                              hipStream_t stream) {
    const float* x      = (const float*)d_in[0];
    const float* fc1w   = (const float*)d_in[1];
    const float* fc1b   = (const float*)d_in[2];
    const float* r1wihf = (const float*)d_in[3];
    const float* r1whhf = (const float*)d_in[4];
    const float* r1bf   = (const float*)d_in[5];
    const float* r1wihb = (const float*)d_in[6];
    const float* r1whhb = (const float*)d_in[7];
    const float* r1bb   = (const float*)d_in[8];
    const float* r2wihf = (const float*)d_in[9];
    const float* r2whhf = (const float*)d_in[10];
    const float* r2bf   = (const float*)d_in[11];
    const float* r2wihb = (const float*)d_in[12];
    const float* r2whhb = (const float*)d_in[13];
    const float* r2bb   = (const float*)d_in[14];
    const float* fc2w   = (const float*)d_in[15];
    const float* fc2b   = (const float*)d_in[16];
    char* ws   = (char*)d_ws;
    float* out = (float*)d_out;

    float*          fc1T  = (float*)(ws + OFF_FC1T);
    unsigned short* XF    = (unsigned short*)(ws + OFF_XF);
    unsigned short* WA1   = (unsigned short*)(ws + OFF_WA1);
    unsigned short* WA2HH = (unsigned short*)(ws + OFF_WA2HH);
    unsigned short* WA2IH = (unsigned short*)(ws + OFF_WA2IH);
    float*          partp = (float*)(ws + OFF_PART);
    float*          BS    = (float*)(ws + OFF_BS);

    k_pre<<<353, 256, 0, stream>>>(r1whhf, r1whhb, r2whhf, r2whhb, r2wihf, r2wihb,
                                   r2bf, r2bb, x, fc1w, fc1b,
                                   WA1, WA2HH, WA2IH, fc1T, partp, BS);
    dim3 gl1(NB1, 2);
    k_lstm1<<<gl1, 256, 0, stream>>>(r1wihf, r1bf, r1wihb, r1bb, WA1, fc1T, XF);
    dim3 gl2(NB2, 2);
    k_lstm2<<<gl2, 512, 0, stream>>>(BS, fc2w, WA2HH, WA2IH, XF, partp);
    k_fc2<<<(BATCH * T2 + 255) / 256, 256, 0, stream>>>(partp, fc2b, out);
}